// Round 15
// baseline (31.633 us; speedup 1.0000x reference)
//
#include <hip/hip_runtime.h>
#include <math.h>

typedef float f32x2 __attribute__((ext_vector_type(2)));

#define A_HEADS 8
#define BB 32
#define HH 160
#define WW 160
#define LOG2E 1.44269504088896340736f

// One thread per output pixel, 12800 waves. Weights read directly (uniform,
// constant-index -> scalar pipe). Conv packed along taps j with log2e
// pre-folded into the patch (exp(logit) == exp2 of scaled logit). Softmax
// num/den accumulated as packed tap-pairs.
__global__ __launch_bounds__(256) void vi_kernel(
    const float* __restrict__ values,
    const float* __restrict__ rewards,
    const float* __restrict__ weight,
    float* __restrict__ out)
{
    int w  = blockIdx.x * 32 + threadIdx.x;   // 0..159 (grid.x = 5)
    int hb = blockIdx.y * 8 + threadIdx.y;    // 0..B*H-1
    int h  = hb % HH;
    int b  = hb / HH;

    const float* vbase = values  + b * (HH * WW);
    const float* rbase = rewards + b * (HH * WW);

    // 3x3 zero-padded patch of rv = values + rewards around (h, w)
    float patch[9];
    #pragma unroll
    for (int di = 0; di < 3; ++di) {
        int hh = h + di - 1;
        bool hok = (hh >= 0) && (hh < HH);
        #pragma unroll
        for (int dj = 0; dj < 3; ++dj) {
            int ww = w + dj - 1;
            bool ok = hok && (ww >= 0) && (ww < WW);
            float val = 0.0f;
            if (ok) {
                int off = hh * WW + ww;
                val = vbase[off] + rbase[off];
            }
            patch[di * 3 + dj] = val;
        }
    }

    // tap pairs: pp = raw (for num), plp = *log2e (for conv logits)
    f32x2 pp[4], plp[4];
    const f32x2 l2e = (f32x2){LOG2E, LOG2E};
    #pragma unroll
    for (int j2 = 0; j2 < 4; ++j2) {
        pp[j2]  = (f32x2){patch[2 * j2], patch[2 * j2 + 1]};
        plp[j2] = pp[j2] * l2e;
    }
    float p8  = patch[8];
    float p8l = p8 * LOG2E;

    float best = -INFINITY;
    #pragma unroll
    for (int a = 0; a < A_HEADS; ++a) {
        // 9 logits (pre-scaled by log2e)
        float lg[9];
        #pragma unroll
        for (int i = 0; i < 9; ++i) {
            const float* wr = weight + (a * 9 + i) * 9;   // uniform row base
            f32x2 acc2 = (f32x2){0.0f, 0.0f};
            #pragma unroll
            for (int j2 = 0; j2 < 4; ++j2) {
                // adjacent uniform pair -> SGPR pair operand for v_pk_fma_f32
                f32x2 wpair = (f32x2){wr[2 * j2], wr[2 * j2 + 1]};
                acc2 = __builtin_elementwise_fma(plp[j2], wpair, acc2);
            }
            lg[i] = acc2.x + acc2.y + p8l * wr[8];
        }
        // softmax accumulate in packed tap pairs: nd_num=(sum p*e), nd_den=(sum e)
        f32x2 nd_num = (f32x2){0.0f, 0.0f};
        f32x2 nd_den = (f32x2){0.0f, 0.0f};
        #pragma unroll
        for (int i2 = 0; i2 < 4; ++i2) {
            f32x2 e2;
            e2.x = __builtin_exp2f(lg[2 * i2]);
            e2.y = __builtin_exp2f(lg[2 * i2 + 1]);
            nd_num = __builtin_elementwise_fma(pp[i2], e2, nd_num);
            nd_den += e2;
        }
        float e8  = __builtin_exp2f(lg[8]);
        float num = nd_num.x + nd_num.y + p8 * e8;
        float den = nd_den.x + nd_den.y + e8;
        best = fmaxf(best, num * __builtin_amdgcn_rcpf(den));
    }

    out[hb * WW + w] = best;
}

extern "C" void kernel_launch(void* const* d_in, const int* in_sizes, int n_in,
                              void* d_out, int out_size, void* d_ws, size_t ws_size,
                              hipStream_t stream)
{
    const float* values  = (const float*)d_in[0];
    const float* rewards = (const float*)d_in[1];
    const float* weight  = (const float*)d_in[2];
    float* out = (float*)d_out;

    dim3 block(32, 8);
    dim3 grid(WW / 32, (BB * HH) / 8);   // (5, 640) -> 3200 blocks, 12800 waves
    vi_kernel<<<grid, block, 0, stream>>>(values, rewards, weight, out);
}

// Round 16
// 30.609 us; speedup vs baseline: 1.0334x; 1.0334x over previous
//
#include <hip/hip_runtime.h>
#include <math.h>

typedef float f32x2 __attribute__((ext_vector_type(2)));

#define A_HEADS 8
#define BB 32
#define HH 160
#define WW 160
#define LOG2E 1.44269504088896340736f

// One thread per output pixel, 12800 waves. Weights read directly (uniform,
// constant-index -> scalar pipe). Conv packed along taps j; log2e folded into
// the conv patch pairs so exp(logit) == v_exp_f32 (exp2) directly.
// Structure identical to the 25.5us round-14 kernel: each logit's exp and
// den/num accumulation consumed immediately inside the i-loop.
__global__ __launch_bounds__(256) void vi_kernel(
    const float* __restrict__ values,
    const float* __restrict__ rewards,
    const float* __restrict__ weight,
    float* __restrict__ out)
{
    int w  = blockIdx.x * 32 + threadIdx.x;   // 0..159 (grid.x = 5)
    int hb = blockIdx.y * 8 + threadIdx.y;    // 0..B*H-1
    int h  = hb % HH;
    int b  = hb / HH;

    const float* vbase = values  + b * (HH * WW);
    const float* rbase = rewards + b * (HH * WW);

    // 3x3 zero-padded patch of rv = values + rewards around (h, w)
    float patch[9];
    #pragma unroll
    for (int di = 0; di < 3; ++di) {
        int hh = h + di - 1;
        bool hok = (hh >= 0) && (hh < HH);
        #pragma unroll
        for (int dj = 0; dj < 3; ++dj) {
            int ww = w + dj - 1;
            bool ok = hok && (ww >= 0) && (ww < WW);
            float val = 0.0f;
            if (ok) {
                int off = hh * WW + ww;
                val = vbase[off] + rbase[off];
            }
            patch[di * 3 + dj] = val;
        }
    }

    // conv tap pairs pre-scaled by log2e (so logits come out in log2 domain)
    f32x2 plp[4];
    #pragma unroll
    for (int j2 = 0; j2 < 4; ++j2)
        plp[j2] = (f32x2){patch[2 * j2] * LOG2E, patch[2 * j2 + 1] * LOG2E};
    float p8l = patch[8] * LOG2E;

    float best = -INFINITY;
    #pragma unroll
    for (int a = 0; a < A_HEADS; ++a) {
        float den = 0.0f;
        float num = 0.0f;
        #pragma unroll
        for (int i = 0; i < 9; ++i) {
            const float* wr = weight + (a * 9 + i) * 9;   // uniform row base
            f32x2 acc2 = (f32x2){0.0f, 0.0f};
            #pragma unroll
            for (int j2 = 0; j2 < 4; ++j2) {
                // adjacent uniform pair -> SGPR pair operand for v_pk_fma_f32
                f32x2 wpair = (f32x2){wr[2 * j2], wr[2 * j2 + 1]};
                acc2 = __builtin_elementwise_fma(plp[j2], wpair, acc2);
            }
            float logit = acc2.x + acc2.y;
            logit = fmaf(p8l, wr[8], logit);
            // logit is pre-scaled by log2e: exp(raw) == exp2(logit)
            float e = __builtin_exp2f(logit);
            den += e;
            num = fmaf(patch[i], e, num);
        }
        best = fmaxf(best, num * __builtin_amdgcn_rcpf(den));
    }

    out[hb * WW + w] = best;
}

extern "C" void kernel_launch(void* const* d_in, const int* in_sizes, int n_in,
                              void* d_out, int out_size, void* d_ws, size_t ws_size,
                              hipStream_t stream)
{
    const float* values  = (const float*)d_in[0];
    const float* rewards = (const float*)d_in[1];
    const float* weight  = (const float*)d_in[2];
    float* out = (float*)d_out;

    dim3 block(32, 8);
    dim3 grid(WW / 32, (BB * HH) / 8);   // (5, 640) -> 3200 blocks, 12800 waves
    vi_kernel<<<grid, block, 0, stream>>>(values, rewards, weight, out);
}

// Round 17
// 25.564 us; speedup vs baseline: 1.2374x; 1.1974x over previous
//
#include <hip/hip_runtime.h>
#include <math.h>

typedef float f32x2 __attribute__((ext_vector_type(2)));

#define A_HEADS 8
#define BB 32
#define HH 160
#define WW 160

// One thread per output pixel, 12800 waves. Weights read directly (uniform,
// constant-index -> scalar pipe). Conv packed along taps j: per logit
// 4 x v_pk_fma_f32 + horizontal add + tail fma (6 slots instead of 9).
__global__ __launch_bounds__(256) void vi_kernel(
    const float* __restrict__ values,
    const float* __restrict__ rewards,
    const float* __restrict__ weight,
    float* __restrict__ out)
{
    int w  = blockIdx.x * 32 + threadIdx.x;   // 0..159 (grid.x = 5)
    int hb = blockIdx.y * 8 + threadIdx.y;    // 0..B*H-1
    int h  = hb % HH;
    int b  = hb / HH;

    const float* vbase = values  + b * (HH * WW);
    const float* rbase = rewards + b * (HH * WW);

    // 3x3 zero-padded patch of rv = values + rewards around (h, w)
    float patch[9];
    #pragma unroll
    for (int di = 0; di < 3; ++di) {
        int hh = h + di - 1;
        bool hok = (hh >= 0) && (hh < HH);
        #pragma unroll
        for (int dj = 0; dj < 3; ++dj) {
            int ww = w + dj - 1;
            bool ok = hok && (ww >= 0) && (ww < WW);
            float val = 0.0f;
            if (ok) {
                int off = hh * WW + ww;
                val = vbase[off] + rbase[off];
            }
            patch[di * 3 + dj] = val;
        }
    }

    // patch pairs (j, j+1), built once, reused by all 72 logits
    f32x2 patchp[4];
    #pragma unroll
    for (int j2 = 0; j2 < 4; ++j2)
        patchp[j2] = (f32x2){patch[2 * j2], patch[2 * j2 + 1]};

    float best = -INFINITY;
    #pragma unroll
    for (int a = 0; a < A_HEADS; ++a) {
        float den = 0.0f;
        float num = 0.0f;
        #pragma unroll
        for (int i = 0; i < 9; ++i) {
            const float* wr = weight + (a * 9 + i) * 9;   // uniform row base
            f32x2 acc2 = (f32x2){0.0f, 0.0f};
            #pragma unroll
            for (int j2 = 0; j2 < 4; ++j2) {
                // adjacent uniform pair -> SGPR pair operand for v_pk_fma_f32
                f32x2 wpair = (f32x2){wr[2 * j2], wr[2 * j2 + 1]};
                acc2 = __builtin_elementwise_fma(patchp[j2], wpair, acc2);
            }
            float logit = acc2.x + acc2.y;
            logit = fmaf(patch[8], wr[8], logit);
            // softmax without max-subtraction (shift-invariant, logits O(few))
            float e = __expf(logit);
            den += e;
            num = fmaf(patch[i], e, num);
        }
        best = fmaxf(best, num * __builtin_amdgcn_rcpf(den));
    }

    out[hb * WW + w] = best;
}

extern "C" void kernel_launch(void* const* d_in, const int* in_sizes, int n_in,
                              void* d_out, int out_size, void* d_ws, size_t ws_size,
                              hipStream_t stream)
{
    const float* values  = (const float*)d_in[0];
    const float* rewards = (const float*)d_in[1];
    const float* weight  = (const float*)d_in[2];
    float* out = (float*)d_out;

    dim3 block(32, 8);
    dim3 grid(WW / 32, (BB * HH) / 8);   // (5, 640) -> 3200 blocks, 12800 waves
    vi_kernel<<<grid, block, 0, stream>>>(values, rewards, weight, out);
}